// Round 19
// baseline (239.422 us; speedup 1.0000x reference)
//
#include <hip/hip_runtime.h>
#include <hip/hip_bf16.h>

typedef __attribute__((ext_vector_type(8))) short short8;
typedef __attribute__((ext_vector_type(4))) float f32x4;
typedef __attribute__((ext_vector_type(2))) float f32x2;

// ---- workspace layout (bytes), 12 MB total ----
#define WS_ZE     0u            // bf16 ze-hi [B][N][64] : 1 MB
#define WS_B1H    (1u<<20)      // matmul1 A-frag image (hi): 1 MB
#define WS_B2     (2u<<20)      // matmul2 A-frag image (hi): 1 MB
#define WS_ZN2    (3u<<20)      // f32 [B][N] 32 KB
#define WS_BS2    ((3u<<20)+32768u) // f32 [K][S] 32 KB
#define WS_ZQP    (4u<<20)      // f32 partial zq: 4 x 2 MB

__device__ __forceinline__ unsigned short f2bf(float x) {
  __hip_bfloat16 h = __float2bfloat16(x);
  return __builtin_bit_cast(unsigned short, h);
}
// LDS-only barrier: does NOT drain vmcnt -> global stores stay in flight
__device__ __forceinline__ void lds_barrier() {
  asm volatile("s_waitcnt lgkmcnt(0)" ::: "memory");
  __builtin_amdgcn_s_barrier();
}

// ---------------- merged prep: ze / bnorm / b1 / b2 by block range ----------------
__global__ __launch_bounds__(256) void prep_all_k(const float* __restrict__ ze,
                                                  const float* __restrict__ books,
                                                  const float* __restrict__ lpq,
                                                  char* __restrict__ ws,
                                                  float* __restrict__ d_out) {
  const int bb = blockIdx.x;
  if (bb < 32) {
    // ---- ze -> bf16 hi + row norms ----
    int t = bb * 256 + threadIdx.x;
    const f32x4* row = (const f32x4*)(ze + t * 64);
    unsigned short* dh = (unsigned short*)(ws + WS_ZE) + t * 64;
    float s = 0.f;
#pragma unroll
    for (int c = 0; c < 8; ++c) {
      const f32x4 v0 = row[2 * c], v1 = row[2 * c + 1];
      union { unsigned short u[8]; short8 v; } H;
#pragma unroll
      for (int r = 0; r < 4; ++r) {
        float a = v0[r]; s += a * a; H.u[r] = f2bf(a);
        float b = v1[r]; s += b * b; H.u[4 + r] = f2bf(b);
      }
      *(short8*)(dh + c * 8) = H.v;
    }
    ((float*)(ws + WS_ZN2))[t] = s;
  } else if (bb < 64) {
    // ---- book norms + precision ----
    int t = (bb - 32) * 256 + threadIdx.x;
    if (t == 0) d_out[524288] = 0.5f / fmaxf(expf(lpq[0]), 1e-10f);
    const f32x4* row = (const f32x4*)(books + t * 64);
    float s = 0.f;
#pragma unroll
    for (int c = 0; c < 16; ++c) {
      const f32x4 v = row[c];
#pragma unroll
      for (int r = 0; r < 4; ++r) s += v[r] * v[r];
    }
    ((float*)(ws + WS_BS2))[t] = s;
  } else if (bb < 320) {
    // ---- matmul1 A-frag image (hi only) ----
    int t = (bb - 64) * 256 + threadIdx.x;
    const int sl = t & 15, g = (t >> 4) & 3, f = (t >> 6) & 1, tt = (t >> 7) & 31, k = t >> 12;
    const float* src = books + ((k * 512 + tt * 16 + sl) * 64 + f * 32 + g * 8);
    const f32x4 v0 = *(const f32x4*)(src);
    const f32x4 v1 = *(const f32x4*)(src + 4);
    union { unsigned short u[8]; short8 v; } H;
#pragma unroll
    for (int r = 0; r < 4; ++r) { H.u[r] = f2bf(v0[r]); H.u[4 + r] = f2bf(v1[r]); }
    *(short8*)(ws + WS_B1H + (k * 32 + tt) * 2048 + f * 1024 + (sl + g * 16) * 16) = H.v;
  } else {
    // ---- matmul2 A-frag image ----
    int t = (bb - 320) * 256 + threadIdx.x;
    const int l15 = t & 15, sub = (t >> 4) & 3, m = (t >> 6) & 3, w = (t >> 8) & 7,
              hh = (t >> 11) & 1, k = t >> 12;
    const float* src = books + ((k * 512 + hh * 256 + w * 32 + sub * 8) * 64 + m * 16 + l15);
    union { unsigned short u[8]; short8 v; } H;
#pragma unroll
    for (int j = 0; j < 8; ++j) H.u[j] = f2bf(src[j * 64]);
    *(short8*)(ws + WS_B2 + k * 65536 + ((hh * 8 + w) * 4 + m) * 1024 + (l15 + sub * 16) * 16) = H.v;
  }
}

// ---------------- zq partial reduce (4 partials) ----------------
__global__ __launch_bounds__(256) void zq_red_k(const char* __restrict__ ws,
                                                float* __restrict__ d_out) {
  int t = blockIdx.x * 256 + threadIdx.x;
  const f32x4 a = *(const f32x4*)(ws + WS_ZQP + t * 16);
  const f32x4 b = *(const f32x4*)(ws + WS_ZQP + (2u << 20) + t * 16);
  const f32x4 c = *(const f32x4*)(ws + WS_ZQP + (4u << 20) + t * 16);
  const f32x4 d = *(const f32x4*)(ws + WS_ZQP + (6u << 20) + t * 16);
  *(f32x4*)(d_out + t * 4) = (a + b) + (c + d);
}

// ---------------- main: 32-row tiles, 1024 threads, 2 blocks/CU (32 waves/CU) ----------------
// LDS: logits f32 [32] rows x 2064 B (enc bf16 overlays row head) + esc 128 = 66176 B
__global__ __launch_bounds__(1024, 2)
void gvq_main(const float* __restrict__ gum, const float* __restrict__ cprobs,
              const float* __restrict__ lpq, char* __restrict__ ws,
              float* __restrict__ d_out) {
  __shared__ char lds[66176];
  char* lgb = lds;                          // 32 logits rows (enc aliases row head)
  float* scr_esc = (float*)(lds + 66048);   // [32] per-row esc = cp/z2

  const int tid  = threadIdx.x;
  const int lane = tid & 63;
  const int wave = tid >> 6;       // 0..15
  const int w8   = wave & 7;
  const int nh   = wave >> 3;      // n-half 0/1
  const int l15  = lane & 15;
  const int g4   = lane >> 4;

  const int bid = blockIdx.x;               // 1024 blocks
  const unsigned kg = (unsigned)bid & 3u;
  const int bt  = bid >> 2;                 // 0..255
  const int b   = bt >> 5;
  const int nt0 = (bt & 31) * 32;
  const int kbeg = (int)kg * 4;

  const float prec  = 0.5f / fmaxf(expf(lpq[0]), 1e-10f);
  const float prec2 = 2.0f * prec;
  const float C24   = 3.7751345442790977e-11f;   // exp(-24)

  // phase-A z-frags for this wave's n-half
  const unsigned short* zh = (const unsigned short*)(ws + WS_ZE)
      + (b * 1024 + nt0 + nh * 16 + l15) * 64;
  const short8 zf0h = *(const short8*)(zh + g4 * 8);
  const short8 zf1h = *(const short8*)(zh + 32 + g4 * 8);
  const float zn2p = ((const float*)(ws + WS_ZN2))[b * 1024 + nt0 + nh * 16 + l15] * prec;

  f32x4 zacc[4] = {{0,0,0,0},{0,0,0,0},{0,0,0,0},{0,0,0,0}};

  const int nr0 = wave * 2, nr1 = wave * 2 + 1;   // phase-B rows (0..31)

#pragma unroll 1
  for (int kk = 0; kk < 4; ++kk) {
    const int k = kbeg + kk;
    const float cp = cprobs[b * 16 + k];
    const char* b1h = ws + WS_B1H + k * 65536;
    const char* b2  = ws + WS_B2  + k * 65536;
    const float* bs2k = (const float*)(ws + WS_BS2) + k * 512;
    const long row0 = ((long)((b * 16 + k) * 1024) + nt0 + nr0) * 512;
    const long row1 = ((long)((b * 16 + k) * 1024) + nt0 + nr1) * 512;

    // ---- phase A: bf16 logits -> LDS tile (each wave: 4 stiles of its n-half) ----
#pragma unroll
    for (int i = 0; i < 4; ++i) {
      const int t = w8 * 4 + i;
      const char* bh = b1h + t * 2048 + lane * 16;
      const short8 a0h = *(const short8*)(bh);
      const short8 a1h = *(const short8*)(bh + 1024);
      f32x4 c = {0.f, 0.f, 0.f, 0.f};
      c = __builtin_amdgcn_mfma_f32_16x16x32_bf16(a0h, zf0h, c, 0, 0, 0);
      c = __builtin_amdgcn_mfma_f32_16x16x32_bf16(a1h, zf1h, c, 0, 0, 0);
      const f32x4 bs2v = *(const f32x4*)(bs2k + t * 16 + g4 * 4);
      f32x4 lv;
#pragma unroll
      for (int r = 0; r < 4; ++r)
        lv[r] = fmaf(c[r], prec2, fmaf(bs2v[r], -prec, -zn2p));
      *(f32x4*)(lgb + (nh * 16 + l15) * 2064 + (t * 16 + g4 * 4) * 4) = lv;
    }
    lds_barrier();                      // barrier 1: logits ready

    // ---- phase B: 2 full rows per wave; dword nt streams ----
#pragma unroll
    for (int r = 0; r < 2; ++r) {
      const int n = r ? nr1 : nr0;
      const long rowb = r ? row1 : row0;
      float uv[8];
#pragma unroll
      for (int j = 0; j < 8; ++j)
        uv[j] = __builtin_nontemporal_load(gum + rowb + j * 64 + lane);

      float Lv[8];
      const float* l32 = (const float*)(lgb + n * 2064);
#pragma unroll
      for (int j = 0; j < 8; ++j) Lv[j] = l32[j * 64 + lane];

      float m = Lv[0];
#pragma unroll
      for (int j = 1; j < 8; ++j) m = fmaxf(m, Lv[j]);
#pragma unroll
      for (int o = 1; o < 64; o <<= 1) m = fmaxf(m, __shfl_xor(m, o));

      unsigned short* er = (unsigned short*)(lgb + n * 2064);
      float z1 = 0.f, z2 = 0.f;
#pragma unroll
      for (int j = 0; j < 8; ++j) {
        const float e1 = __expf(Lv[j] - m); z1 += e1;
        const float L  = 1e-10f - __logf(uv[j] + 1e-10f);
        const float rl = __builtin_amdgcn_rcpf(L);
        const float e2 = (e1 * e1) * (rl * rl) * C24;
        z2 += e2;
        er[j * 64 + lane] = f2bf(e2);
      }
#pragma unroll
      for (int o = 1; o < 64; o <<= 1) {
        z1 += __shfl_xor(z1, o);
        z2 += __shfl_xor(z2, o);
      }
      const float c1 = m + __logf(z1);
      if (lane == 0) scr_esc[n] = cp / z2;

      float* pp = d_out + 524289 + rowb;
      float* pl = pp + 67108864;
#pragma unroll
      for (int j = 0; j < 8; ++j) {
        const float lpv = Lv[j] - c1;
        __builtin_nontemporal_store(__expf(lpv), pp + j * 64 + lane);
        __builtin_nontemporal_store(lpv, pl + j * 64 + lane);
      }
    }
    lds_barrier();                      // barrier 2: enc + esc ready

    // ---- phase C: cacc = booksT . encT (own n-half), zacc += cacc * esc ----
    {
      f32x4 cacc[4] = {{0,0,0,0},{0,0,0,0},{0,0,0,0},{0,0,0,0}};
#pragma unroll
      for (int h = 0; h < 2; ++h) {
        const short8 bf = *(const short8*)(lgb + (nh * 16 + l15) * 2064 +
                                           (h * 256 + w8 * 32 + g4 * 8) * 2);
        const char* afb = b2 + ((h * 8 + w8) * 4) * 1024 + lane * 16;
#pragma unroll
        for (int m = 0; m < 4; ++m) {
          const short8 af = *(const short8*)(afb + m * 1024);
          cacc[m] = __builtin_amdgcn_mfma_f32_16x16x32_bf16(af, bf, cacc[m], 0, 0, 0);
        }
      }
      const float esc = scr_esc[nh * 16 + l15];
#pragma unroll
      for (int m = 0; m < 4; ++m)
#pragma unroll
        for (int r = 0; r < 4; ++r) zacc[m][r] = fmaf(cacc[m][r], esc, zacc[m][r]);
    }
    lds_barrier();                      // barrier 3: enc reads done before next A overwrites
  }

  // ---- zq cross-wave reduce (8 waves per n-half) + partial write ----
  __syncthreads();
#pragma unroll
  for (int m = 0; m < 4; ++m)
    *(f32x4*)(lds + wave * 4096 + l15 * 256 + m * 64 + g4 * 16) = zacc[m];
  __syncthreads();
  const int e = tid * 2;                    // 0..2046 over 32x64 elems
  const int nn = e >> 6, d4 = (e & 63) * 4;
  const int base = (nn >> 4) * 8;           // waves of this n-half
  f32x2 acc = {0.f, 0.f};
#pragma unroll
  for (int w = 0; w < 8; ++w)
    acc += *(const f32x2*)(lds + (base + w) * 4096 + (nn & 15) * 256 + d4);
  *(f32x2*)(ws + WS_ZQP + kg * (2u << 20) +
            (((unsigned)(b * 1024 + nt0)) * 64 + e) * 4) = acc;
}

extern "C" void kernel_launch(void* const* d_in, const int* in_sizes, int n_in,
                              void* d_out, int out_size, void* d_ws, size_t ws_size,
                              hipStream_t stream) {
  (void)in_sizes; (void)n_in; (void)out_size; (void)ws_size;
  const float* ze     = (const float*)d_in[0];
  const float* cprobs = (const float*)d_in[1];
  const float* books  = (const float*)d_in[2];
  const float* lpq    = (const float*)d_in[3];
  const float* gum    = (const float*)d_in[4];
  float* out = (float*)d_out;
  char* ws = (char*)d_ws;
  hipLaunchKernelGGL(prep_all_k, dim3(576),  dim3(256),  0, stream, ze, books, lpq, ws, out);
  hipLaunchKernelGGL(gvq_main,   dim3(1024), dim3(1024), 0, stream, gum, cprobs, lpq, ws, out);
  hipLaunchKernelGGL(zq_red_k,   dim3(512),  dim3(256),  0, stream, ws, out);
}

// Round 20
// 237.877 us; speedup vs baseline: 1.0065x; 1.0065x over previous
//
#include <hip/hip_runtime.h>
#include <hip/hip_bf16.h>

typedef __attribute__((ext_vector_type(8))) short short8;
typedef __attribute__((ext_vector_type(4))) float f32x4;
typedef __attribute__((ext_vector_type(2))) float f32x2;

// ---- workspace layout (bytes), 10 MB total ----
#define WS_ZE     0u            // bf16 ze-hi [B][N][64] : 1 MB
#define WS_B1H    (1u<<20)      // matmul1 A-frag image (hi): 1 MB
#define WS_B2     (2u<<20)      // matmul2 A-frag image (hi): 1 MB
#define WS_ZN2    (3u<<20)      // f32 [B][N] 32 KB
#define WS_BS2    ((3u<<20)+32768u) // f32 [K][S] 32 KB
#define WS_ZQP    (4u<<20)      // f32 partial zq: 3 x 2 MB

__device__ __forceinline__ unsigned short f2bf(float x) {
  __hip_bfloat16 h = __float2bfloat16(x);
  return __builtin_bit_cast(unsigned short, h);
}
// LDS-only barrier: does NOT drain vmcnt -> global stores stay in flight
__device__ __forceinline__ void lds_barrier() {
  asm volatile("s_waitcnt lgkmcnt(0)" ::: "memory");
  __builtin_amdgcn_s_barrier();
}

// ---------------- merged prep: ze / bnorm / b1 / b2 by block range ----------------
__global__ __launch_bounds__(256) void prep_all_k(const float* __restrict__ ze,
                                                  const float* __restrict__ books,
                                                  const float* __restrict__ lpq,
                                                  char* __restrict__ ws,
                                                  float* __restrict__ d_out) {
  const int bb = blockIdx.x;
  if (bb < 32) {
    int t = bb * 256 + threadIdx.x;
    const f32x4* row = (const f32x4*)(ze + t * 64);
    unsigned short* dh = (unsigned short*)(ws + WS_ZE) + t * 64;
    float s = 0.f;
#pragma unroll
    for (int c = 0; c < 8; ++c) {
      const f32x4 v0 = row[2 * c], v1 = row[2 * c + 1];
      union { unsigned short u[8]; short8 v; } H;
#pragma unroll
      for (int r = 0; r < 4; ++r) {
        float a = v0[r]; s += a * a; H.u[r] = f2bf(a);
        float b = v1[r]; s += b * b; H.u[4 + r] = f2bf(b);
      }
      *(short8*)(dh + c * 8) = H.v;
    }
    ((float*)(ws + WS_ZN2))[t] = s;
  } else if (bb < 64) {
    int t = (bb - 32) * 256 + threadIdx.x;
    if (t == 0) d_out[524288] = 0.5f / fmaxf(expf(lpq[0]), 1e-10f);
    const f32x4* row = (const f32x4*)(books + t * 64);
    float s = 0.f;
#pragma unroll
    for (int c = 0; c < 16; ++c) {
      const f32x4 v = row[c];
#pragma unroll
      for (int r = 0; r < 4; ++r) s += v[r] * v[r];
    }
    ((float*)(ws + WS_BS2))[t] = s;
  } else if (bb < 320) {
    int t = (bb - 64) * 256 + threadIdx.x;
    const int sl = t & 15, g = (t >> 4) & 3, f = (t >> 6) & 1, tt = (t >> 7) & 31, k = t >> 12;
    const float* src = books + ((k * 512 + tt * 16 + sl) * 64 + f * 32 + g * 8);
    const f32x4 v0 = *(const f32x4*)(src);
    const f32x4 v1 = *(const f32x4*)(src + 4);
    union { unsigned short u[8]; short8 v; } H;
#pragma unroll
    for (int r = 0; r < 4; ++r) { H.u[r] = f2bf(v0[r]); H.u[4 + r] = f2bf(v1[r]); }
    *(short8*)(ws + WS_B1H + (k * 32 + tt) * 2048 + f * 1024 + (sl + g * 16) * 16) = H.v;
  } else {
    int t = (bb - 320) * 256 + threadIdx.x;
    const int l15 = t & 15, sub = (t >> 4) & 3, m = (t >> 6) & 3, w = (t >> 8) & 7,
              hh = (t >> 11) & 1, k = t >> 12;
    const float* src = books + ((k * 512 + hh * 256 + w * 32 + sub * 8) * 64 + m * 16 + l15);
    union { unsigned short u[8]; short8 v; } H;
#pragma unroll
    for (int j = 0; j < 8; ++j) H.u[j] = f2bf(src[j * 64]);
    *(short8*)(ws + WS_B2 + k * 65536 + ((hh * 8 + w) * 4 + m) * 1024 + (l15 + sub * 16) * 16) = H.v;
  }
}

// ---------------- zq partial reduce (3 partials) ----------------
__global__ __launch_bounds__(256) void zq_red_k(const char* __restrict__ ws,
                                                float* __restrict__ d_out) {
  int t = blockIdx.x * 256 + threadIdx.x;
  const f32x4 a = *(const f32x4*)(ws + WS_ZQP + t * 16);
  const f32x4 b = *(const f32x4*)(ws + WS_ZQP + (2u << 20) + t * 16);
  const f32x4 c = *(const f32x4*)(ws + WS_ZQP + (4u << 20) + t * 16);
  *(f32x4*)(d_out + t * 4) = a + b + c;
}

// ---------------- main: gumbel pipelined one iter ahead; 3 blocks/CU ----------------
// LDS: logits f32 [16] rows x 2064 B (enc bf16 overlays row head) + esc 64 = 33088 B
__global__ __launch_bounds__(512, 3)
void gvq_main(const float* __restrict__ gum, const float* __restrict__ cprobs,
              const float* __restrict__ lpq, char* __restrict__ ws,
              float* __restrict__ d_out) {
  __shared__ char lds[33088];
  char* lgb = lds;
  float* scr_esc = (float*)(lds + 33024);

  const int tid  = threadIdx.x;
  const int lane = tid & 63;
  const int wave = tid >> 6;
  const int l15  = lane & 15;
  const int g4   = lane >> 4;

  const int bid = blockIdx.x;               // 1536 blocks
  const unsigned kg = (unsigned)bid % 3u;
  const int bt  = (int)((unsigned)bid / 3u);  // 0..511
  const int b   = bt >> 6;
  const int n0  = (bt & 63) * 16;
  const int kbeg = (kg == 0) ? 0 : (kg == 1 ? 6 : 11);
  const int kcnt = (kg == 0) ? 6 : 5;

  const float prec  = 0.5f / fmaxf(expf(lpq[0]), 1e-10f);
  const float prec2 = 2.0f * prec;
  const float C24   = 3.7751345442790977e-11f;   // exp(-24)

  const unsigned short* zh = (const unsigned short*)(ws + WS_ZE) + (b * 1024 + n0 + l15) * 64;
  const short8 zf0h = *(const short8*)(zh + g4 * 8);
  const short8 zf1h = *(const short8*)(zh + 32 + g4 * 8);
  const float zn2p = ((const float*)(ws + WS_ZN2))[b * 1024 + n0 + l15] * prec;

  f32x4 zacc[4] = {{0,0,0,0},{0,0,0,0},{0,0,0,0},{0,0,0,0}};

  const int nr0 = wave * 2, nr1 = wave * 2 + 1;
  const long rowbase0 = ((long)(b * 16) * 1024 + n0 + nr0) * 512;
  const long rowbase1 = ((long)(b * 16) * 1024 + n0 + nr1) * 512;

  // ---- prologue: gumbel for first iter ----
  float uva[8], uvb[8];
  {
    const long r0 = rowbase0 + (long)kbeg * 524288;
    const long r1 = rowbase1 + (long)kbeg * 524288;
#pragma unroll
    for (int j = 0; j < 8; ++j)
      uva[j] = __builtin_nontemporal_load(gum + r0 + j * 64 + lane);
#pragma unroll
    for (int j = 0; j < 8; ++j)
      uvb[j] = __builtin_nontemporal_load(gum + r1 + j * 64 + lane);
  }

#pragma unroll 1
  for (int kk = 0; kk < kcnt; ++kk) {
    const int k = kbeg + kk;
    const float cp = cprobs[b * 16 + k];
    const char* b1h = ws + WS_B1H + k * 65536;
    const char* b2  = ws + WS_B2  + k * 65536;
    const float* bs2k = (const float*)(ws + WS_BS2) + k * 512;
    const long row0 = rowbase0 + (long)k * 524288;
    const long row1 = rowbase1 + (long)k * 524288;

    // ---- phase A: bf16 logits -> LDS tile ----
#pragma unroll
    for (int i = 0; i < 4; ++i) {
      const int t = wave * 4 + i;
      const char* bh = b1h + t * 2048 + lane * 16;
      const short8 a0h = *(const short8*)(bh);
      const short8 a1h = *(const short8*)(bh + 1024);
      f32x4 c = {0.f, 0.f, 0.f, 0.f};
      c = __builtin_amdgcn_mfma_f32_16x16x32_bf16(a0h, zf0h, c, 0, 0, 0);
      c = __builtin_amdgcn_mfma_f32_16x16x32_bf16(a1h, zf1h, c, 0, 0, 0);
      const f32x4 bs2v = *(const f32x4*)(bs2k + t * 16 + g4 * 4);
      f32x4 lv;
#pragma unroll
      for (int r = 0; r < 4; ++r)
        lv[r] = fmaf(c[r], prec2, fmaf(bs2v[r], -prec, -zn2p));
      *(f32x4*)(lgb + l15 * 2064 + (t * 16 + g4 * 4) * 4) = lv;
    }
    lds_barrier();                      // barrier 1: logits ready

    // ---- phase B: 2 full rows per wave; uses prefetched gumbel ----
#pragma unroll
    for (int r = 0; r < 2; ++r) {
      const int n = r ? nr1 : nr0;
      const long rowb = r ? row1 : row0;

      float Lv[8];
      const float* l32 = (const float*)(lgb + n * 2064);
#pragma unroll
      for (int j = 0; j < 8; ++j) Lv[j] = l32[j * 64 + lane];

      float m = Lv[0];
#pragma unroll
      for (int j = 1; j < 8; ++j) m = fmaxf(m, Lv[j]);
#pragma unroll
      for (int o = 1; o < 64; o <<= 1) m = fmaxf(m, __shfl_xor(m, o));

      unsigned short* er = (unsigned short*)(lgb + n * 2064);
      float z1 = 0.f, z2 = 0.f;
#pragma unroll
      for (int j = 0; j < 8; ++j) {
        const float u = r ? uvb[j] : uva[j];
        const float e1 = __expf(Lv[j] - m); z1 += e1;
        const float L  = 1e-10f - __logf(u + 1e-10f);
        const float rl = __builtin_amdgcn_rcpf(L);
        const float e2 = (e1 * e1) * (rl * rl) * C24;
        z2 += e2;
        er[j * 64 + lane] = f2bf(e2);
      }
#pragma unroll
      for (int o = 1; o < 64; o <<= 1) {
        z1 += __shfl_xor(z1, o);
        z2 += __shfl_xor(z2, o);
      }
      const float c1 = m + __logf(z1);
      if (lane == 0) scr_esc[n] = cp / z2;

      float* pp = d_out + 524289 + rowb;
      float* pl = pp + 67108864;
#pragma unroll
      for (int j = 0; j < 8; ++j) {
        const float lpv = Lv[j] - c1;
        __builtin_nontemporal_store(__expf(lpv), pp + j * 64 + lane);
        __builtin_nontemporal_store(lpv, pl + j * 64 + lane);
      }
    }
    lds_barrier();                      // barrier 2: enc + esc ready

    // ---- prefetch next iter's gumbel: flies through C + barrier3 + next A ----
    if (kk + 1 < kcnt) {
      const long rn0 = rowbase0 + (long)(k + 1) * 524288;
      const long rn1 = rowbase1 + (long)(k + 1) * 524288;
#pragma unroll
      for (int j = 0; j < 8; ++j)
        uva[j] = __builtin_nontemporal_load(gum + rn0 + j * 64 + lane);
#pragma unroll
      for (int j = 0; j < 8; ++j)
        uvb[j] = __builtin_nontemporal_load(gum + rn1 + j * 64 + lane);
    }

    // ---- phase C: cacc = booksT . encT, zacc += cacc * esc[l15] ----
    {
      f32x4 cacc[4] = {{0,0,0,0},{0,0,0,0},{0,0,0,0},{0,0,0,0}};
#pragma unroll
      for (int h = 0; h < 2; ++h) {
        const short8 bf = *(const short8*)(lgb + l15 * 2064 +
                                           (h * 256 + wave * 32 + g4 * 8) * 2);
        const char* afb = b2 + ((h * 8 + wave) * 4) * 1024 + lane * 16;
#pragma unroll
        for (int m = 0; m < 4; ++m) {
          const short8 af = *(const short8*)(afb + m * 1024);
          cacc[m] = __builtin_amdgcn_mfma_f32_16x16x32_bf16(af, bf, cacc[m], 0, 0, 0);
        }
      }
      const float esc = scr_esc[l15];
#pragma unroll
      for (int m = 0; m < 4; ++m)
#pragma unroll
        for (int r = 0; r < 4; ++r) zacc[m][r] = fmaf(cacc[m][r], esc, zacc[m][r]);
    }
    lds_barrier();                      // barrier 3: enc reads done before next A overwrites
  }

  // ---- zq cross-wave reduce + partial write ----
  __syncthreads();
#pragma unroll
  for (int m = 0; m < 4; ++m)
    *(f32x4*)(lds + wave * 4096 + l15 * 256 + m * 64 + g4 * 16) = zacc[m];
  __syncthreads();
  const int e = tid * 2;
  f32x2 acc = {0.f, 0.f};
#pragma unroll
  for (int w = 0; w < 8; ++w) acc += *(const f32x2*)(lds + w * 4096 + e * 4);
  *(f32x2*)(ws + WS_ZQP + kg * (2u << 20) +
            (((unsigned)(b * 1024 + n0)) * 64 + e) * 4) = acc;
}

extern "C" void kernel_launch(void* const* d_in, const int* in_sizes, int n_in,
                              void* d_out, int out_size, void* d_ws, size_t ws_size,
                              hipStream_t stream) {
  (void)in_sizes; (void)n_in; (void)out_size; (void)ws_size;
  const float* ze     = (const float*)d_in[0];
  const float* cprobs = (const float*)d_in[1];
  const float* books  = (const float*)d_in[2];
  const float* lpq    = (const float*)d_in[3];
  const float* gum    = (const float*)d_in[4];
  float* out = (float*)d_out;
  char* ws = (char*)d_ws;
  hipLaunchKernelGGL(prep_all_k, dim3(576),  dim3(256), 0, stream, ze, books, lpq, ws, out);
  hipLaunchKernelGGL(gvq_main,   dim3(1536), dim3(512), 0, stream, gum, cprobs, lpq, ws, out);
  hipLaunchKernelGGL(zq_red_k,   dim3(512),  dim3(256), 0, stream, ws, out);
}

// Round 21
// 222.562 us; speedup vs baseline: 1.0758x; 1.0688x over previous
//
#include <hip/hip_runtime.h>
#include <hip/hip_bf16.h>

typedef __attribute__((ext_vector_type(8))) short short8;
typedef __attribute__((ext_vector_type(4))) float f32x4;
typedef __attribute__((ext_vector_type(2))) float f32x2;

// ---- workspace layout (bytes), 12 MB total ----
#define WS_ZE     0u            // bf16 ze-hi [B][N][64] : 1 MB
#define WS_B1H    (1u<<20)      // matmul1 A-frag image (hi): 1 MB
#define WS_B2     (2u<<20)      // matmul2 A-frag image (hi): 1 MB
#define WS_ZN2    (3u<<20)      // f32 [B][N] 32 KB
#define WS_BS2    ((3u<<20)+32768u) // f32 [K][S] 32 KB
#define WS_ZQP    (4u<<20)      // f32 partial zq: 4 x 2 MB

__device__ __forceinline__ unsigned short f2bf(float x) {
  __hip_bfloat16 h = __float2bfloat16(x);
  return __builtin_bit_cast(unsigned short, h);
}
// LDS-only barrier: does NOT drain vmcnt -> global stores stay in flight
__device__ __forceinline__ void lds_barrier() {
  asm volatile("s_waitcnt lgkmcnt(0)" ::: "memory");
  __builtin_amdgcn_s_barrier();
}

// ---------------- merged prep: ze / bnorm / b1 / b2 by block range ----------------
__global__ __launch_bounds__(256) void prep_all_k(const float* __restrict__ ze,
                                                  const float* __restrict__ books,
                                                  const float* __restrict__ lpq,
                                                  char* __restrict__ ws,
                                                  float* __restrict__ d_out) {
  const int bb = blockIdx.x;
  if (bb < 32) {
    // ---- ze -> bf16 hi + row norms ----
    int t = bb * 256 + threadIdx.x;
    const f32x4* row = (const f32x4*)(ze + t * 64);
    unsigned short* dh = (unsigned short*)(ws + WS_ZE) + t * 64;
    float s = 0.f;
#pragma unroll
    for (int c = 0; c < 8; ++c) {
      const f32x4 v0 = row[2 * c], v1 = row[2 * c + 1];
      union { unsigned short u[8]; short8 v; } H;
#pragma unroll
      for (int r = 0; r < 4; ++r) {
        float a = v0[r]; s += a * a; H.u[r] = f2bf(a);
        float b = v1[r]; s += b * b; H.u[4 + r] = f2bf(b);
      }
      *(short8*)(dh + c * 8) = H.v;
    }
    ((float*)(ws + WS_ZN2))[t] = s;
  } else if (bb < 64) {
    // ---- book norms + precision ----
    int t = (bb - 32) * 256 + threadIdx.x;
    if (t == 0) d_out[524288] = 0.5f / fmaxf(expf(lpq[0]), 1e-10f);
    const f32x4* row = (const f32x4*)(books + t * 64);
    float s = 0.f;
#pragma unroll
    for (int c = 0; c < 16; ++c) {
      const f32x4 v = row[c];
#pragma unroll
      for (int r = 0; r < 4; ++r) s += v[r] * v[r];
    }
    ((float*)(ws + WS_BS2))[t] = s;
  } else if (bb < 320) {
    // ---- matmul1 A-frag image (hi only) ----
    int t = (bb - 64) * 256 + threadIdx.x;
    const int sl = t & 15, g = (t >> 4) & 3, f = (t >> 6) & 1, tt = (t >> 7) & 31, k = t >> 12;
    const float* src = books + ((k * 512 + tt * 16 + sl) * 64 + f * 32 + g * 8);
    const f32x4 v0 = *(const f32x4*)(src);
    const f32x4 v1 = *(const f32x4*)(src + 4);
    union { unsigned short u[8]; short8 v; } H;
#pragma unroll
    for (int r = 0; r < 4; ++r) { H.u[r] = f2bf(v0[r]); H.u[4 + r] = f2bf(v1[r]); }
    *(short8*)(ws + WS_B1H + (k * 32 + tt) * 2048 + f * 1024 + (sl + g * 16) * 16) = H.v;
  } else {
    // ---- matmul2 A-frag image ----
    int t = (bb - 320) * 256 + threadIdx.x;
    const int l15 = t & 15, sub = (t >> 4) & 3, m = (t >> 6) & 3, w = (t >> 8) & 7,
              hh = (t >> 11) & 1, k = t >> 12;
    const float* src = books + ((k * 512 + hh * 256 + w * 32 + sub * 8) * 64 + m * 16 + l15);
    union { unsigned short u[8]; short8 v; } H;
#pragma unroll
    for (int j = 0; j < 8; ++j) H.u[j] = f2bf(src[j * 64]);
    *(short8*)(ws + WS_B2 + k * 65536 + ((hh * 8 + w) * 4 + m) * 1024 + (l15 + sub * 16) * 16) = H.v;
  }
}

// ---------------- zq partial reduce (4 partials) ----------------
__global__ __launch_bounds__(256) void zq_red_k(const char* __restrict__ ws,
                                                float* __restrict__ d_out) {
  int t = blockIdx.x * 256 + threadIdx.x;
  const f32x4 a = *(const f32x4*)(ws + WS_ZQP + t * 16);
  const f32x4 b = *(const f32x4*)(ws + WS_ZQP + (2u << 20) + t * 16);
  const f32x4 c = *(const f32x4*)(ws + WS_ZQP + (4u << 20) + t * 16);
  const f32x4 d = *(const f32x4*)(ws + WS_ZQP + (6u << 20) + t * 16);
  *(f32x4*)(d_out + t * 4) = (a + b) + (c + d);
}

// ---------------- main: R18 base, stores CACHED (A/B vs NT), 4 blocks/CU ----------------
// LDS: logits f32 [16] rows x 2064 B (enc bf16 overlays first 1024 B of each row) + esc 64 = 33088 B
__global__ __launch_bounds__(512, 4)
void gvq_main(const float* __restrict__ gum, const float* __restrict__ cprobs,
              const float* __restrict__ lpq, char* __restrict__ ws,
              float* __restrict__ d_out) {
  __shared__ char lds[33088];
  char* lgb = lds;                          // logits tile rows (enc aliases row head)
  float* scr_esc = (float*)(lds + 33024);   // [16] per-row esc = cp/z2

  const int tid  = threadIdx.x;
  const int lane = tid & 63;
  const int wave = tid >> 6;
  const int l15  = lane & 15;
  const int g4   = lane >> 4;

  const int bid = blockIdx.x;               // 2048 blocks
  const unsigned kg = ((unsigned)bid & 7u) >> 1;          // XCD-pair-aligned k-group
  const int bt  = ((bid >> 3) << 1) | (bid & 1);          // 0..511
  const int b   = bt >> 6;
  const int n0  = (bt & 63) * 16;
  const int kbeg = (int)kg * 4;

  const float prec  = 0.5f / fmaxf(expf(lpq[0]), 1e-10f);
  const float prec2 = 2.0f * prec;
  const float C24   = 3.7751345442790977e-11f;   // exp(-24)

  const unsigned short* zh = (const unsigned short*)(ws + WS_ZE) + (b * 1024 + n0 + l15) * 64;
  const short8 zf0h = *(const short8*)(zh + g4 * 8);
  const short8 zf1h = *(const short8*)(zh + 32 + g4 * 8);
  const float zn2p = ((const float*)(ws + WS_ZN2))[b * 1024 + n0 + l15] * prec;

  f32x4 zacc[4] = {{0,0,0,0},{0,0,0,0},{0,0,0,0},{0,0,0,0}};

  const int nr0 = wave * 2, nr1 = wave * 2 + 1;

#pragma unroll 1
  for (int kk = 0; kk < 4; ++kk) {
    const int k = kbeg + kk;
    const float cp = cprobs[b * 16 + k];
    const char* b1h = ws + WS_B1H + k * 65536;
    const char* b2  = ws + WS_B2  + k * 65536;
    const float* bs2k = (const float*)(ws + WS_BS2) + k * 512;
    const long row0 = ((long)((b * 16 + k) * 1024) + n0 + nr0) * 512;
    const long row1 = ((long)((b * 16 + k) * 1024) + n0 + nr1) * 512;

    // ---- phase A: bf16 logits -> LDS tile ----
#pragma unroll
    for (int i = 0; i < 4; ++i) {
      const int t = wave * 4 + i;
      const char* bh = b1h + t * 2048 + lane * 16;
      const short8 a0h = *(const short8*)(bh);
      const short8 a1h = *(const short8*)(bh + 1024);
      f32x4 c = {0.f, 0.f, 0.f, 0.f};
      c = __builtin_amdgcn_mfma_f32_16x16x32_bf16(a0h, zf0h, c, 0, 0, 0);
      c = __builtin_amdgcn_mfma_f32_16x16x32_bf16(a1h, zf1h, c, 0, 0, 0);
      const f32x4 bs2v = *(const f32x4*)(bs2k + t * 16 + g4 * 4);
      f32x4 lv;
#pragma unroll
      for (int r = 0; r < 4; ++r)
        lv[r] = fmaf(c[r], prec2, fmaf(bs2v[r], -prec, -zn2p));
      *(f32x4*)(lgb + l15 * 2064 + (t * 16 + g4 * 4) * 4) = lv;
    }
    lds_barrier();                      // barrier 1: logits ready

    // ---- phase B: 2 full rows per wave; dword streams ----
#pragma unroll
    for (int r = 0; r < 2; ++r) {
      const int n = r ? nr1 : nr0;
      const long rowb = r ? row1 : row0;
      // gumbel loads: NT (read-once, keep out of L2)
      float uv[8];
#pragma unroll
      for (int j = 0; j < 8; ++j)
        uv[j] = __builtin_nontemporal_load(gum + rowb + j * 64 + lane);

      float Lv[8];
      const float* l32 = (const float*)(lgb + n * 2064);
#pragma unroll
      for (int j = 0; j < 8; ++j) Lv[j] = l32[j * 64 + lane];

      // full-row max
      float m = Lv[0];
#pragma unroll
      for (int j = 1; j < 8; ++j) m = fmaxf(m, Lv[j]);
#pragma unroll
      for (int o = 1; o < 64; o <<= 1) m = fmaxf(m, __shfl_xor(m, o));

      // e1 (transient); e2 unscaled (bound-max m2 = 2m+24) -> enc aliased in row head
      unsigned short* er = (unsigned short*)(lgb + n * 2064);
      float z1 = 0.f, z2 = 0.f;
#pragma unroll
      for (int j = 0; j < 8; ++j) {
        const float e1 = __expf(Lv[j] - m); z1 += e1;
        const float L  = 1e-10f - __logf(uv[j] + 1e-10f);
        const float rl = __builtin_amdgcn_rcpf(L);
        const float e2 = (e1 * e1) * (rl * rl) * C24;
        z2 += e2;
        er[j * 64 + lane] = f2bf(e2);
      }
#pragma unroll
      for (int o = 1; o < 64; o <<= 1) {
        z1 += __shfl_xor(z1, o);
        z2 += __shfl_xor(z2, o);
      }
      const float c1 = m + __logf(z1);
      if (lane == 0) scr_esc[n] = cp / z2;

      // CACHED dword stores (A/B vs R18's NT): L2 aggregates and drains smoothly
      float* pp = d_out + 524289 + rowb;
      float* pl = pp + 67108864;
#pragma unroll
      for (int j = 0; j < 8; ++j) {
        const float lpv = Lv[j] - c1;
        pp[j * 64 + lane] = __expf(lpv);
        pl[j * 64 + lane] = lpv;
      }
    }
    lds_barrier();                      // barrier 2: enc + esc ready

    // ---- phase C: cacc = booksT . encT, zacc += cacc * esc[l15] ----
    {
      f32x4 cacc[4] = {{0,0,0,0},{0,0,0,0},{0,0,0,0},{0,0,0,0}};
#pragma unroll
      for (int h = 0; h < 2; ++h) {
        const short8 bf = *(const short8*)(lgb + l15 * 2064 +
                                           (h * 256 + wave * 32 + g4 * 8) * 2);
        const char* afb = b2 + ((h * 8 + wave) * 4) * 1024 + lane * 16;
#pragma unroll
        for (int m = 0; m < 4; ++m) {
          const short8 af = *(const short8*)(afb + m * 1024);
          cacc[m] = __builtin_amdgcn_mfma_f32_16x16x32_bf16(af, bf, cacc[m], 0, 0, 0);
        }
      }
      const float esc = scr_esc[l15];
#pragma unroll
      for (int m = 0; m < 4; ++m)
#pragma unroll
        for (int r = 0; r < 4; ++r) zacc[m][r] = fmaf(cacc[m][r], esc, zacc[m][r]);
    }
    lds_barrier();                      // barrier 3: enc reads done before next A overwrites
  }

  // ---- zq cross-wave reduce + partial write ----
  __syncthreads();
#pragma unroll
  for (int m = 0; m < 4; ++m)
    *(f32x4*)(lds + wave * 4096 + l15 * 256 + m * 64 + g4 * 16) = zacc[m];
  __syncthreads();
  const int e = tid * 2;
  f32x2 acc = {0.f, 0.f};
#pragma unroll
  for (int w = 0; w < 8; ++w) acc += *(const f32x2*)(lds + w * 4096 + e * 4);
  *(f32x2*)(ws + WS_ZQP + kg * (2u << 20) +
            (((unsigned)(b * 1024 + n0)) * 64 + e) * 4) = acc;
}

extern "C" void kernel_launch(void* const* d_in, const int* in_sizes, int n_in,
                              void* d_out, int out_size, void* d_ws, size_t ws_size,
                              hipStream_t stream) {
  (void)in_sizes; (void)n_in; (void)out_size; (void)ws_size;
  const float* ze     = (const float*)d_in[0];
  const float* cprobs = (const float*)d_in[1];
  const float* books  = (const float*)d_in[2];
  const float* lpq    = (const float*)d_in[3];
  const float* gum    = (const float*)d_in[4];
  float* out = (float*)d_out;
  char* ws = (char*)d_ws;
  hipLaunchKernelGGL(prep_all_k, dim3(576),  dim3(256), 0, stream, ze, books, lpq, ws, out);
  hipLaunchKernelGGL(gvq_main,   dim3(2048), dim3(512), 0, stream, gum, cprobs, lpq, ws, out);
  hipLaunchKernelGGL(zq_red_k,   dim3(512),  dim3(256), 0, stream, ws, out);
}